// Round 1
// baseline (1434.208 us; speedup 1.0000x reference)
//
#include <hip/hip_runtime.h>
#include <hip/hip_bf16.h>

typedef unsigned short u16;
typedef __bf16 bf16x8 __attribute__((ext_vector_type(8)));
typedef float f32x4 __attribute__((ext_vector_type(4)));
typedef unsigned short us8v __attribute__((ext_vector_type(8)));

// Problem constants (fixed by reference)
#define NN1 2048
#define NN2 2048
#define DD  256

static __device__ __forceinline__ float bf2f(u16 u) {
  return __uint_as_float(((unsigned int)u) << 16);
}
static __device__ __forceinline__ u16 f2bf(float f) {
  __hip_bfloat16 h = __float2bfloat16(f);
  return __builtin_bit_cast(u16, h);
}

// block = 256 threads (4 waves)
static __device__ __forceinline__ float block_reduce_sum(float v) {
#pragma unroll
  for (int off = 32; off > 0; off >>= 1) v += __shfl_down(v, off, 64);
  __shared__ float tmp[4];
  const int tid = threadIdx.x;
  if ((tid & 63) == 0) tmp[tid >> 6] = v;
  __syncthreads();
  return tmp[0] + tmp[1] + tmp[2] + tmp[3];
}

static __device__ __forceinline__ void gload_lds16(const u16* g, u16* l) {
  __builtin_amdgcn_global_load_lds(
      (__attribute__((address_space(1))) void*)g,
      (__attribute__((address_space(3))) void*)l, 16, 0, 0);
}

// ---------------------------------------------------------------------------
// NT bf16 GEMM: C[m,n] = sum_k A[m,k]*B[n,k], A:[M,K] row-major, B:[N,K] row-major
// BM=BN=128, BK=32, 256 threads (4 waves, each computes 64x64 via 4x4 16x16 frags)
// MODE 0: out = bf16(acc)                       (T = c1 @ s)
// MODE 1: out = f32 exp(-acc)                   (inter_c)
// MODE 2: out = bf16 exp(-20*(inter + 0.01*(c1a[r]+bc2[c]-2*acc)))   (K)
// ---------------------------------------------------------------------------
template <int MODE>
__global__ __launch_bounds__(256) void gemm_nt(
    const u16* __restrict__ A, const u16* __restrict__ B,
    int K, int lda, int ldb, int ldo, void* __restrict__ outp,
    const float* __restrict__ interp, const float* __restrict__ c1a,
    const float* __restrict__ bc2) {
  __shared__ __align__(16) u16 As[128 * 32];
  __shared__ __align__(16) u16 Bs[128 * 32];
  const int tid = threadIdx.x;
  const int lane = tid & 63;
  const int w = tid >> 6;
  const int m0 = blockIdx.y * 128;
  const int n0 = blockIdx.x * 128;
  const int wr = (w >> 1) * 64;
  const int wc = (w & 1) * 64;

  // staging: per wave, issue p in {0,1}: 16 rows x 64B each
  const int srow = w * 16 + (lane >> 2);
  const int scol = (lane & 3) * 8;

  f32x4 acc[4][4] = {};

  for (int k0 = 0; k0 < K; k0 += 32) {
#pragma unroll
    for (int p = 0; p < 2; ++p) {
      gload_lds16(A + (size_t)(m0 + p * 64 + srow) * lda + (k0 + scol),
                  &As[(p * 64 + w * 16) * 32]);
      gload_lds16(B + (size_t)(n0 + p * 64 + srow) * ldb + (k0 + scol),
                  &Bs[(p * 64 + w * 16) * 32]);
    }
    __syncthreads();
    bf16x8 af[4], bg[4];
#pragma unroll
    for (int m = 0; m < 4; ++m)
      af[m] = *(const bf16x8*)&As[(wr + m * 16 + (lane & 15)) * 32 + (lane >> 4) * 8];
#pragma unroll
    for (int n = 0; n < 4; ++n)
      bg[n] = *(const bf16x8*)&Bs[(wc + n * 16 + (lane & 15)) * 32 + (lane >> 4) * 8];
#pragma unroll
    for (int m = 0; m < 4; ++m)
#pragma unroll
      for (int n = 0; n < 4; ++n)
        acc[m][n] = __builtin_amdgcn_mfma_f32_16x16x32_bf16(af[m], bg[n], acc[m][n], 0, 0, 0);
    __syncthreads();
  }

  // C/D layout (verified): col = lane&15, row = (lane>>4)*4 + r
  const int cr = (lane >> 4) * 4;
  const int cc = lane & 15;
#pragma unroll
  for (int m = 0; m < 4; ++m) {
#pragma unroll
    for (int n = 0; n < 4; ++n) {
      const int gc = n0 + wc + n * 16 + cc;
#pragma unroll
      for (int r = 0; r < 4; ++r) {
        const int gr = m0 + wr + m * 16 + cr + r;
        const float val = acc[m][n][r];
        if constexpr (MODE == 0) {
          ((u16*)outp)[(size_t)gr * ldo + gc] = f2bf(val);
        } else if constexpr (MODE == 1) {
          ((float*)outp)[(size_t)gr * ldo + gc] = __expf(-val);
        } else {
          const float cost =
              interp[(size_t)gr * ldo + gc] + 0.01f * (c1a[gr] + bc2[gc] - 2.0f * val);
          ((u16*)outp)[(size_t)gr * ldo + gc] = f2bf(__expf(-20.0f * cost));
        }
      }
    }
  }
}

// ---------------------------------------------------------------------------
// y = M @ x (row-major bf16 M [2048][2048]), out[row] = anum / y[row]
// ---------------------------------------------------------------------------
__global__ __launch_bounds__(256) void matvec_div(const u16* __restrict__ M,
                                                  const float* __restrict__ x,
                                                  float* __restrict__ outv, float anum) {
  const int row = blockIdx.x;
  const int tid = threadIdx.x;
  const u16* rp = M + (size_t)row * NN2;
  us8v kv = *(const us8v*)&rp[tid * 8];
  float4 x0 = *(const float4*)&x[tid * 8];
  float4 x1 = *(const float4*)&x[tid * 8 + 4];
  float p = bf2f(kv[0]) * x0.x + bf2f(kv[1]) * x0.y + bf2f(kv[2]) * x0.z +
            bf2f(kv[3]) * x0.w + bf2f(kv[4]) * x1.x + bf2f(kv[5]) * x1.y +
            bf2f(kv[6]) * x1.z + bf2f(kv[7]) * x1.w;
  float s = block_reduce_sum(p);
  if (tid == 0) outv[row] = anum / s;
}

// ---------------------------------------------------------------------------
// bf16 transpose, 64x64 LDS tiles
// ---------------------------------------------------------------------------
__global__ __launch_bounds__(256) void transpose_bf(const u16* __restrict__ in,
                                                    u16* __restrict__ outp) {
  __shared__ u16 t[64][65];
  const int r0 = blockIdx.y * 64, c0 = blockIdx.x * 64;
  const int tid = threadIdx.x;
#pragma unroll
  for (int i = 0; i < 16; ++i) {
    const int idx = i * 256 + tid;
    const int r = idx >> 6, c = idx & 63;
    t[r][c] = in[(size_t)(r0 + r) * NN2 + c0 + c];
  }
  __syncthreads();
#pragma unroll
  for (int i = 0; i < 16; ++i) {
    const int idx = i * 256 + tid;
    const int r = idx >> 6, c = idx & 63;
    outp[(size_t)(c0 + r) * NN1 + r0 + c] = t[c][r];
  }
}

// ---------------------------------------------------------------------------
// s = 0.05*s + 0.95*u[i]*K[i,j]*v[j]; also writes sT (bf16, transposed) for GEMM#1
// ---------------------------------------------------------------------------
__global__ __launch_bounds__(256) void supdate(float* __restrict__ s, u16* __restrict__ sT,
                                               const u16* __restrict__ Kb,
                                               const float* __restrict__ u,
                                               const float* __restrict__ v) {
  __shared__ u16 t[64][65];
  const int r0 = blockIdx.y * 64, c0 = blockIdx.x * 64;
  const int tid = threadIdx.x;
#pragma unroll
  for (int i = 0; i < 16; ++i) {
    const int idx = i * 256 + tid;
    const int r = idx >> 6, c = idx & 63;
    const size_t off = (size_t)(r0 + r) * NN2 + c0 + c;
    const float sv = 0.05f * s[off] + 0.95f * u[r0 + r] * bf2f(Kb[off]) * v[c0 + c];
    s[off] = sv;
    t[r][c] = f2bf(sv);
  }
  __syncthreads();
#pragma unroll
  for (int i = 0; i < 16; ++i) {
    const int idx = i * 256 + tid;
    const int r = idx >> 6, c = idx & 63;
    sT[(size_t)(c0 + r) * NN1 + r0 + c] = t[c][r];
  }
}

// ---------------------------------------------------------------------------
// per-row: bf16 convert + optional rowsum of squares * (1/2048)
// ---------------------------------------------------------------------------
__global__ __launch_bounds__(256) void conv_rowsq(const float* __restrict__ in,
                                                  u16* __restrict__ outb,
                                                  float* __restrict__ rowsq) {
  const int row = blockIdx.x;
  const int tid = threadIdx.x;
  const float* rp = in + (size_t)row * NN2;
  u16* op = outb + (size_t)row * NN2;
  float4 v0 = *(const float4*)&rp[tid * 8];
  float4 v1 = *(const float4*)&rp[tid * 8 + 4];
  us8v o;
  o[0] = f2bf(v0.x); o[1] = f2bf(v0.y); o[2] = f2bf(v0.z); o[3] = f2bf(v0.w);
  o[4] = f2bf(v1.x); o[5] = f2bf(v1.y); o[6] = f2bf(v1.z); o[7] = f2bf(v1.w);
  *(us8v*)&op[tid * 8] = o;
  float ss = v0.x * v0.x + v0.y * v0.y + v0.z * v0.z + v0.w * v0.w +
             v1.x * v1.x + v1.y * v1.y + v1.z * v1.z + v1.w * v1.w;
  float tot = block_reduce_sum(ss);
  if (rowsq != nullptr && tid == 0) rowsq[row] = tot * (1.0f / 2048.0f);
}

__global__ __launch_bounds__(256) void convbf(const float* __restrict__ in,
                                              u16* __restrict__ outb) {
  const int i = (blockIdx.x * 256 + threadIdx.x) * 8;
  float4 v0 = *(const float4*)&in[i];
  float4 v1 = *(const float4*)&in[i + 4];
  us8v o;
  o[0] = f2bf(v0.x); o[1] = f2bf(v0.y); o[2] = f2bf(v0.z); o[3] = f2bf(v0.w);
  o[4] = f2bf(v1.x); o[5] = f2bf(v1.y); o[6] = f2bf(v1.z); o[7] = f2bf(v1.w);
  *(us8v*)&outb[i] = o;
}

__global__ __launch_bounds__(256) void sinit(float* __restrict__ s, u16* __restrict__ sT) {
  const int i = (blockIdx.x * 256 + threadIdx.x) * 8;
  const float val = 1.0f / (2048.0f * 2048.0f);
  float4 f; f.x = f.y = f.z = f.w = val;
  *(float4*)&s[i] = f;
  *(float4*)&s[i + 4] = f;
  const u16 b = f2bf(val);
  us8v o; o[0] = o[1] = o[2] = o[3] = o[4] = o[5] = o[6] = o[7] = b;
  *(us8v*)&sT[i] = o;
}

__global__ __launch_bounds__(256) void init_uv(float* __restrict__ u, float* __restrict__ v,
                                               float* __restrict__ dout) {
  const int i = blockIdx.x * 256 + threadIdx.x;
  if (i < NN1) u[i] = 1.0f / 2048.0f;
  if (i < NN2) v[i] = 1.0f / 2048.0f;
  if (i == 0) dout[0] = 0.0f;
}

// column sums of c2^2, two-stage (deterministic, no atomics)
__global__ __launch_bounds__(256) void colsq_part(const float* __restrict__ c2,
                                                  float* __restrict__ part) {
  const int col = blockIdx.x * 256 + threadIdx.x;
  const int rb = blockIdx.y;
  float acc = 0.0f;
  for (int r = rb * 128; r < rb * 128 + 128; ++r) {
    const float x = c2[(size_t)r * NN2 + col];
    acc += x * x;
  }
  part[(size_t)rb * NN2 + col] = acc;
}
__global__ __launch_bounds__(256) void colsq_reduce(const float* __restrict__ part,
                                                    float* __restrict__ bc2) {
  const int col = blockIdx.x * 256 + threadIdx.x;
  float s = 0.0f;
#pragma unroll
  for (int rb = 0; rb < 16; ++rb) s += part[(size_t)rb * NN2 + col];
  bc2[col] = s * (1.0f / 2048.0f);
}

__global__ __launch_bounds__(256) void lossdot(const float* __restrict__ inter,
                                               const float* __restrict__ s,
                                               float* __restrict__ partial) {
  const int row = blockIdx.x;
  const int tid = threadIdx.x;
  const size_t base = (size_t)row * NN2 + tid * 8;
  float4 a0 = *(const float4*)&inter[base];
  float4 a1 = *(const float4*)&inter[base + 4];
  float4 b0 = *(const float4*)&s[base];
  float4 b1 = *(const float4*)&s[base + 4];
  float p = a0.x * b0.x + a0.y * b0.y + a0.z * b0.z + a0.w * b0.w +
            a1.x * b1.x + a1.y * b1.y + a1.z * b1.z + a1.w * b1.w;
  float t = block_reduce_sum(p);
  if (tid == 0) partial[row] = t;
}
__global__ __launch_bounds__(256) void lossreduce(const float* __restrict__ partial,
                                                  float* __restrict__ dout) {
  float p = 0.0f;
  for (int i = threadIdx.x; i < NN1; i += 256) p += partial[i];
  float t = block_reduce_sum(p);
  if (threadIdx.x == 0) dout[0] = -t;
}

// ---------------------------------------------------------------------------
// workspace layout (bytes)
// ---------------------------------------------------------------------------
#define OFF_C1B   ((size_t)0)
#define OFF_C2B   ((size_t)8388608)
#define OFF_T     ((size_t)16777216)
#define OFF_ST    ((size_t)25165824)
#define OFF_KB    ((size_t)33554432)
#define OFF_KTB   ((size_t)41943040)
#define OFF_O1B   ((size_t)50331648)
#define OFF_O2B   ((size_t)51380224)
#define OFF_INTER ((size_t)52428800)
#define OFF_S     ((size_t)69206016)
#define OFF_C1A   ((size_t)85983232)
#define OFF_BC2   ((size_t)85991424)
#define OFF_U     ((size_t)85999616)
#define OFF_V     ((size_t)86007808)
#define OFF_PART  ((size_t)86016000)

extern "C" void kernel_launch(void* const* d_in, const int* in_sizes, int n_in,
                              void* d_out, int out_size, void* d_ws, size_t ws_size,
                              hipStream_t stream) {
  (void)in_sizes; (void)n_in; (void)out_size; (void)ws_size;
  const float* out1 = (const float*)d_in[0];
  const float* out2 = (const float*)d_in[1];
  const float* c1 = (const float*)d_in[2];
  const float* c2 = (const float*)d_in[3];
  float* dout = (float*)d_out;
  char* ws = (char*)d_ws;

  u16* c1b = (u16*)(ws + OFF_C1B);
  u16* c2b = (u16*)(ws + OFF_C2B);
  u16* T = (u16*)(ws + OFF_T);
  u16* sT = (u16*)(ws + OFF_ST);
  u16* Kb = (u16*)(ws + OFF_KB);
  u16* KTb = (u16*)(ws + OFF_KTB);
  u16* o1b = (u16*)(ws + OFF_O1B);
  u16* o2b = (u16*)(ws + OFF_O2B);
  float* inter = (float*)(ws + OFF_INTER);
  float* s = (float*)(ws + OFF_S);
  float* c1a = (float*)(ws + OFF_C1A);
  float* bc2 = (float*)(ws + OFF_BC2);
  float* u = (float*)(ws + OFF_U);
  float* v = (float*)(ws + OFF_V);
  float* part = (float*)(ws + OFF_PART);

  // ---- prep ----
  init_uv<<<8, 256, 0, stream>>>(u, v, dout);
  conv_rowsq<<<NN1, 256, 0, stream>>>(c1, c1b, c1a);
  conv_rowsq<<<NN2, 256, 0, stream>>>(c2, c2b, nullptr);
  colsq_part<<<dim3(8, 16), 256, 0, stream>>>(c2, part);
  colsq_reduce<<<8, 256, 0, stream>>>(part, bc2);
  convbf<<<256, 256, 0, stream>>>(out1, o1b);   // 2048*256 elems
  convbf<<<256, 256, 0, stream>>>(out2, o2b);
  sinit<<<2048, 256, 0, stream>>>(s, sT);
  // inter_c = exp(-(out1 @ out2^T))
  gemm_nt<1><<<dim3(16, 16), 256, 0, stream>>>(o1b, o2b, DD, DD, DD, NN2, (void*)inter,
                                               nullptr, nullptr, nullptr);

  // ---- outer loop ----
  for (int t = 0; t < 10; ++t) {
    // T = c1 @ s  (NT with B = sT)
    gemm_nt<0><<<dim3(16, 16), 256, 0, stream>>>(c1b, sT, NN1, NN1, NN1, NN2, (void*)T,
                                                 nullptr, nullptr, nullptr);
    // K = exp(-20*(inter + 0.01*(c1a + bc2 - 2*(T @ c2^T))))
    gemm_nt<2><<<dim3(16, 16), 256, 0, stream>>>(T, c2b, NN2, NN2, NN2, NN2, (void*)Kb,
                                                 inter, c1a, bc2);
    transpose_bf<<<dim3(32, 32), 256, 0, stream>>>(Kb, KTb);
    for (int it = 0; it < 5; ++it) {
      matvec_div<<<NN1, 256, 0, stream>>>(Kb, v, u, 1.0f / 2048.0f);
      matvec_div<<<NN2, 256, 0, stream>>>(KTb, u, v, 1.0f / 2048.0f);
    }
    supdate<<<dim3(32, 32), 256, 0, stream>>>(s, sT, Kb, u, v);
  }

  // ---- loss = -sum(inter * s) ----
  lossdot<<<NN1, 256, 0, stream>>>(inter, s, part);
  lossreduce<<<1, 256, 0, stream>>>(part, dout);
}

// Round 2
// 1013.643 us; speedup vs baseline: 1.4149x; 1.4149x over previous
//
#include <hip/hip_runtime.h>
#include <hip/hip_bf16.h>

typedef unsigned short u16;
typedef __bf16 bf16x8 __attribute__((ext_vector_type(8)));
typedef float f32x4 __attribute__((ext_vector_type(4)));
typedef unsigned short us8v __attribute__((ext_vector_type(8)));

#define NN1 2048
#define NN2 2048
#define DD  256

static __device__ __forceinline__ float bf2f(u16 u) {
  return __uint_as_float(((unsigned int)u) << 16);
}
static __device__ __forceinline__ u16 f2bf(float f) {
  __hip_bfloat16 h = __float2bfloat16(f);
  return __builtin_bit_cast(u16, h);
}

// block = 256 threads (4 waves)
static __device__ __forceinline__ float block_reduce_sum(float v) {
#pragma unroll
  for (int off = 32; off > 0; off >>= 1) v += __shfl_down(v, off, 64);
  __shared__ float tmp[4];
  const int tid = threadIdx.x;
  if ((tid & 63) == 0) tmp[tid >> 6] = v;
  __syncthreads();
  return tmp[0] + tmp[1] + tmp[2] + tmp[3];
}

static __device__ __forceinline__ void gload_lds16(const u16* g, u16* l) {
  __builtin_amdgcn_global_load_lds(
      (__attribute__((address_space(1))) void*)g,
      (__attribute__((address_space(3))) void*)l, 16, 0, 0);
}

// ---------------------------------------------------------------------------
// NT bf16 GEMM (prep only): out = f32 exp(-(A @ B^T)); A:[M,K], B:[N,K] row-major
// ---------------------------------------------------------------------------
__global__ __launch_bounds__(256) void gemm_nt_exp(
    const u16* __restrict__ A, const u16* __restrict__ B,
    int K, int lda, int ldb, int ldo, float* __restrict__ outp) {
  __shared__ __align__(16) u16 As[128 * 32];
  __shared__ __align__(16) u16 Bs[128 * 32];
  const int tid = threadIdx.x;
  const int lane = tid & 63;
  const int w = tid >> 6;
  const int m0 = blockIdx.y * 128;
  const int n0 = blockIdx.x * 128;
  const int wr = (w >> 1) * 64;
  const int wc = (w & 1) * 64;
  const int srow = w * 16 + (lane >> 2);
  const int scol = (lane & 3) * 8;

  f32x4 acc[4][4] = {};

  for (int k0 = 0; k0 < K; k0 += 32) {
#pragma unroll
    for (int p = 0; p < 2; ++p) {
      gload_lds16(A + (size_t)(m0 + p * 64 + srow) * lda + (k0 + scol),
                  &As[(p * 64 + w * 16) * 32]);
      gload_lds16(B + (size_t)(n0 + p * 64 + srow) * ldb + (k0 + scol),
                  &Bs[(p * 64 + w * 16) * 32]);
    }
    __syncthreads();
    bf16x8 af[4], bg[4];
#pragma unroll
    for (int m = 0; m < 4; ++m)
      af[m] = *(const bf16x8*)&As[(wr + m * 16 + (lane & 15)) * 32 + (lane >> 4) * 8];
#pragma unroll
    for (int n = 0; n < 4; ++n)
      bg[n] = *(const bf16x8*)&Bs[(wc + n * 16 + (lane & 15)) * 32 + (lane >> 4) * 8];
#pragma unroll
    for (int m = 0; m < 4; ++m)
#pragma unroll
      for (int n = 0; n < 4; ++n)
        acc[m][n] = __builtin_amdgcn_mfma_f32_16x16x32_bf16(af[m], bg[n], acc[m][n], 0, 0, 0);
    __syncthreads();
  }

  const int cr = (lane >> 4) * 4;
  const int cc = lane & 15;
#pragma unroll
  for (int m = 0; m < 4; ++m)
#pragma unroll
    for (int n = 0; n < 4; ++n) {
      const int gc = n0 + wc + n * 16 + cc;
#pragma unroll
      for (int r = 0; r < 4; ++r) {
        const int gr = m0 + wr + m * 16 + cr + r;
        outp[(size_t)gr * ldo + gc] = __expf(-acc[m][n][r]);
      }
    }
}

// ---------------------------------------------------------------------------
// CSR build: count -> scan -> ordered fill (all deterministic)
// ---------------------------------------------------------------------------
__global__ __launch_bounds__(256) void csr_count(const float* __restrict__ M,
                                                 int* __restrict__ deg) {
  const int row = blockIdx.x;
  const int tid = threadIdx.x;
  int cnt = 0;
  for (int c = tid; c < 2048; c += 256) cnt += (M[(size_t)row * 2048 + c] != 0.0f);
#pragma unroll
  for (int off = 32; off > 0; off >>= 1) cnt += __shfl_down(cnt, off, 64);
  __shared__ int t4[4];
  if ((tid & 63) == 0) t4[tid >> 6] = cnt;
  __syncthreads();
  if (tid == 0) deg[row] = t4[0] + t4[1] + t4[2] + t4[3];
}

__global__ __launch_bounds__(256) void csr_scan(const int* __restrict__ deg,
                                                int* __restrict__ rptr) {
  __shared__ int sc[256];
  const int t = threadIdx.x;
  int loc[8];
  int tot = 0;
#pragma unroll
  for (int q = 0; q < 8; ++q) { loc[q] = deg[t * 8 + q]; tot += loc[q]; }
  sc[t] = tot;
  __syncthreads();
  for (int off = 1; off < 256; off <<= 1) {
    int val = (t >= off) ? sc[t - off] : 0;
    __syncthreads();
    sc[t] += val;
    __syncthreads();
  }
  int run = sc[t] - tot;  // exclusive
#pragma unroll
  for (int q = 0; q < 8; ++q) { rptr[t * 8 + q] = run; run += loc[q]; }
  if (t == 255) rptr[2048] = run;
}

__global__ __launch_bounds__(256) void csr_fill(const float* __restrict__ M,
                                                const int* __restrict__ rptr,
                                                int2* __restrict__ ent) {
  const int row = blockIdx.x;
  const int tid = threadIdx.x;
  const int lane = tid & 63;
  const int w = tid >> 6;
  __shared__ int wcnt[4];
  __shared__ int basech;
  if (tid == 0) basech = rptr[row];
  __syncthreads();
#pragma unroll 1
  for (int ch = 0; ch < 8; ++ch) {
    const int c = ch * 256 + tid;
    const float v = M[(size_t)row * 2048 + c];
    const bool p = (v != 0.0f);
    const unsigned long long mask = __ballot(p);
    if (lane == 0) wcnt[w] = __popcll(mask);
    __syncthreads();
    int woff = 0;
    for (int x = 0; x < w; ++x) woff += wcnt[x];
    const int pos = basech + woff + __popcll(mask & ((1ull << lane) - 1ull));
    if (p) ent[pos] = make_int2(c, __float_as_int(v));
    __syncthreads();
    if (tid == 0) basech += wcnt[0] + wcnt[1] + wcnt[2] + wcnt[3];
    __syncthreads();
  }
}

// ---------------------------------------------------------------------------
// Row-gather SpMM: out[row,:] = sum_{e in CSR row} val_e * D[col_e, :]
// D bf16 [2048][2048]. EPI 0: out = bf16(acc)  (T = c1 @ s)
// EPI 1: out = bf16 exp(-20*(interT[row,c] + 0.01*(c1a[c] + bc2[row] - 2*acc)))
//         (Kt, from GWt = c2 @ Tt)
// ---------------------------------------------------------------------------
template <int EPI>
__global__ __launch_bounds__(256) void spmm(const int* __restrict__ rptr,
                                            const int2* __restrict__ ent,
                                            const u16* __restrict__ D,
                                            u16* __restrict__ outp,
                                            const float* __restrict__ interT,
                                            const float* __restrict__ c1a,
                                            const float* __restrict__ bc2) {
  const int row = blockIdx.x;
  const int tid = threadIdx.x;
  const int col0 = tid * 8;
  const int beg = rptr[row];
  const int end = rptr[row + 1];
  float acc[8] = {};
  for (int e = beg; e < end; ++e) {
    const int2 kv = ent[e];  // uniform across block -> scalar load
    const float val = __int_as_float(kv.y);
    const us8v sv = *(const us8v*)&D[((size_t)kv.x << 11) + col0];
#pragma unroll
    for (int q = 0; q < 8; ++q) acc[q] += val * bf2f(sv[q]);
  }
  us8v o;
  if constexpr (EPI == 0) {
#pragma unroll
    for (int q = 0; q < 8; ++q) o[q] = f2bf(acc[q]);
  } else {
    const float bcj = bc2[row];
    const size_t base = ((size_t)row << 11) + col0;
    const float4 it0 = *(const float4*)&interT[base];
    const float4 it1 = *(const float4*)&interT[base + 4];
    const float4 a0 = *(const float4*)&c1a[col0];
    const float4 a1 = *(const float4*)&c1a[col0 + 4];
    const float it[8] = {it0.x, it0.y, it0.z, it0.w, it1.x, it1.y, it1.z, it1.w};
    const float aa[8] = {a0.x, a0.y, a0.z, a0.w, a1.x, a1.y, a1.z, a1.w};
#pragma unroll
    for (int q = 0; q < 8; ++q) {
      const float cost = it[q] + 0.01f * (aa[q] + bcj - 2.0f * acc[q]);
      o[q] = f2bf(__expf(-20.0f * cost));
    }
  }
  *(us8v*)&outp[((size_t)row << 11) + col0] = o;
}

// ---------------------------------------------------------------------------
// y = M @ x (row-major bf16 M), out[row] = anum / y[row]
// ---------------------------------------------------------------------------
__global__ __launch_bounds__(256) void matvec_div(const u16* __restrict__ M,
                                                  const float* __restrict__ x,
                                                  float* __restrict__ outv, float anum) {
  const int row = blockIdx.x;
  const int tid = threadIdx.x;
  const u16* rp = M + ((size_t)row << 11);
  us8v kv = *(const us8v*)&rp[tid * 8];
  float4 x0 = *(const float4*)&x[tid * 8];
  float4 x1 = *(const float4*)&x[tid * 8 + 4];
  float p = bf2f(kv[0]) * x0.x + bf2f(kv[1]) * x0.y + bf2f(kv[2]) * x0.z +
            bf2f(kv[3]) * x0.w + bf2f(kv[4]) * x1.x + bf2f(kv[5]) * x1.y +
            bf2f(kv[6]) * x1.z + bf2f(kv[7]) * x1.w;
  float s = block_reduce_sum(p);
  if (tid == 0) outv[row] = anum / s;
}

// ---------------------------------------------------------------------------
// bf16 transpose, 64x64 LDS tiles (square 2048)
// ---------------------------------------------------------------------------
__global__ __launch_bounds__(256) void transpose_bf(const u16* __restrict__ in,
                                                    u16* __restrict__ outp) {
  __shared__ u16 t[64][65];
  const int r0 = blockIdx.y * 64, c0 = blockIdx.x * 64;
  const int tid = threadIdx.x;
#pragma unroll
  for (int i = 0; i < 16; ++i) {
    const int idx = i * 256 + tid;
    const int r = idx >> 6, c = idx & 63;
    t[r][c] = in[(size_t)(r0 + r) * 2048 + c0 + c];
  }
  __syncthreads();
#pragma unroll
  for (int i = 0; i < 16; ++i) {
    const int idx = i * 256 + tid;
    const int r = idx >> 6, c = idx & 63;
    outp[(size_t)(c0 + r) * 2048 + r0 + c] = t[c][r];
  }
}

// ---------------------------------------------------------------------------
// s = 0.05*s + 0.95*u[i]*K[i,j]*v[j]; writes s (f32) and s_bf (bf16, row-major)
// ---------------------------------------------------------------------------
__global__ __launch_bounds__(256) void supdate(float* __restrict__ s,
                                               u16* __restrict__ s_bf,
                                               const u16* __restrict__ Kb,
                                               const float* __restrict__ u,
                                               const float* __restrict__ v) {
  const int row = blockIdx.x;
  const int tid = threadIdx.x;
  const int col0 = tid * 8;
  const float uu = 0.95f * u[row];
  const size_t off = ((size_t)row << 11) + col0;
  us8v kv = *(const us8v*)&Kb[off];
  float4 v0 = *(const float4*)&v[col0];
  float4 v1 = *(const float4*)&v[col0 + 4];
  float4 s0 = *(const float4*)&s[off];
  float4 s1 = *(const float4*)&s[off + 4];
  const float vv[8] = {v0.x, v0.y, v0.z, v0.w, v1.x, v1.y, v1.z, v1.w};
  float sv[8] = {s0.x, s0.y, s0.z, s0.w, s1.x, s1.y, s1.z, s1.w};
  us8v o;
#pragma unroll
  for (int q = 0; q < 8; ++q) {
    sv[q] = 0.05f * sv[q] + uu * bf2f(kv[q]) * vv[q];
    o[q] = f2bf(sv[q]);
  }
  float4 w0 = {sv[0], sv[1], sv[2], sv[3]};
  float4 w1 = {sv[4], sv[5], sv[6], sv[7]};
  *(float4*)&s[off] = w0;
  *(float4*)&s[off + 4] = w1;
  *(us8v*)&s_bf[off] = o;
}

// ---------------------------------------------------------------------------
// small prep kernels
// ---------------------------------------------------------------------------
__global__ __launch_bounds__(256) void rowsq(const float* __restrict__ in,
                                             float* __restrict__ out) {
  const int row = blockIdx.x;
  const int tid = threadIdx.x;
  const float* rp = in + (size_t)row * 2048;
  float4 v0 = *(const float4*)&rp[tid * 8];
  float4 v1 = *(const float4*)&rp[tid * 8 + 4];
  float ss = v0.x * v0.x + v0.y * v0.y + v0.z * v0.z + v0.w * v0.w +
             v1.x * v1.x + v1.y * v1.y + v1.z * v1.z + v1.w * v1.w;
  float tot = block_reduce_sum(ss);
  if (tid == 0) out[row] = tot * (1.0f / 2048.0f);
}

__global__ __launch_bounds__(256) void convbf(const float* __restrict__ in,
                                              u16* __restrict__ outb) {
  const int i = (blockIdx.x * 256 + threadIdx.x) * 8;
  float4 v0 = *(const float4*)&in[i];
  float4 v1 = *(const float4*)&in[i + 4];
  us8v o;
  o[0] = f2bf(v0.x); o[1] = f2bf(v0.y); o[2] = f2bf(v0.z); o[3] = f2bf(v0.w);
  o[4] = f2bf(v1.x); o[5] = f2bf(v1.y); o[6] = f2bf(v1.z); o[7] = f2bf(v1.w);
  *(us8v*)&outb[i] = o;
}

__global__ __launch_bounds__(256) void sinit(float* __restrict__ s, u16* __restrict__ s_bf) {
  const int i = (blockIdx.x * 256 + threadIdx.x) * 8;
  const float val = 1.0f / (2048.0f * 2048.0f);
  float4 f; f.x = f.y = f.z = f.w = val;
  *(float4*)&s[i] = f;
  *(float4*)&s[i + 4] = f;
  const u16 b = f2bf(val);
  us8v o; o[0] = o[1] = o[2] = o[3] = o[4] = o[5] = o[6] = o[7] = b;
  *(us8v*)&s_bf[i] = o;
}

__global__ __launch_bounds__(256) void init_uv(float* __restrict__ u, float* __restrict__ v,
                                               float* __restrict__ dout) {
  const int i = blockIdx.x * 256 + threadIdx.x;
  if (i < NN1) u[i] = 1.0f / 2048.0f;
  if (i < NN2) v[i] = 1.0f / 2048.0f;
  if (i == 0) dout[0] = 0.0f;
}

// column sums of c2^2, two-stage (deterministic, no atomics)
__global__ __launch_bounds__(256) void colsq_part(const float* __restrict__ c2,
                                                  float* __restrict__ part) {
  const int col = blockIdx.x * 256 + threadIdx.x;
  const int rb = blockIdx.y;
  float acc = 0.0f;
  for (int r = rb * 128; r < rb * 128 + 128; ++r) {
    const float x = c2[(size_t)r * 2048 + col];
    acc += x * x;
  }
  part[(size_t)rb * 2048 + col] = acc;
}
__global__ __launch_bounds__(256) void colsq_reduce(const float* __restrict__ part,
                                                    float* __restrict__ bc2) {
  const int col = blockIdx.x * 256 + threadIdx.x;
  float s = 0.0f;
#pragma unroll
  for (int rb = 0; rb < 16; ++rb) s += part[(size_t)rb * 2048 + col];
  bc2[col] = s * (1.0f / 2048.0f);
}

// ---------------------------------------------------------------------------
// loss = -sum(inter * s) computed from interT via LDS-transposing tiled dot
// ---------------------------------------------------------------------------
__global__ __launch_bounds__(256) void lossdot_t(const float* __restrict__ interT,
                                                 const float* __restrict__ s,
                                                 float* __restrict__ partial) {
  __shared__ float t[64][65];
  const int j0 = blockIdx.y * 64, i0 = blockIdx.x * 64;
  const int tid = threadIdx.x;
#pragma unroll
  for (int q = 0; q < 16; ++q) {
    const int idx = q * 256 + tid;
    const int r = idx >> 6, c = idx & 63;
    t[r][c] = interT[(size_t)(j0 + r) * 2048 + i0 + c];
  }
  __syncthreads();
  float acc = 0.0f;
#pragma unroll
  for (int q = 0; q < 16; ++q) {
    const int idx = q * 256 + tid;
    const int r = idx >> 6, c = idx & 63;
    acc += s[(size_t)(i0 + r) * 2048 + j0 + c] * t[c][r];
  }
  float tot = block_reduce_sum(acc);
  if (tid == 0) partial[blockIdx.y * 32 + blockIdx.x] = tot;
}

__global__ __launch_bounds__(256) void lossreduce(const float* __restrict__ partial,
                                                  float* __restrict__ dout) {
  float p = 0.0f;
  for (int i = threadIdx.x; i < 1024; i += 256) p += partial[i];
  float t = block_reduce_sum(p);
  if (threadIdx.x == 0) dout[0] = -t;
}

// ---------------------------------------------------------------------------
// workspace layout (bytes) — total ~76.2 MB
// ---------------------------------------------------------------------------
#define OFF_INTERT ((size_t)0)         // f32 16MB
#define OFF_S      ((size_t)16777216)  // f32 16MB
#define OFF_SBF    ((size_t)33554432)  // bf16 8MB
#define OFF_T      ((size_t)41943040)  // bf16 8MB
#define OFF_TT     ((size_t)50331648)  // bf16 8MB
#define OFF_K      ((size_t)58720256)  // bf16 8MB
#define OFF_KT     ((size_t)67108864)  // bf16 8MB
#define OFF_O1B    ((size_t)75497472)  // bf16 1MB
#define OFF_O2B    ((size_t)76546048)  // bf16 1MB
#define OFF_PART   ((size_t)77594624)  // f32 128KB
#define OFF_C1A    ((size_t)77725696)  // f32 8KB
#define OFF_BC2    ((size_t)77733888)
#define OFF_U      ((size_t)77742080)
#define OFF_V      ((size_t)77750272)
#define OFF_LP     ((size_t)77758464)  // 1024 f32 loss partials
#define OFF_RP1    ((size_t)77766656)  // 2049 ints
#define OFF_RP2    ((size_t)77783040)
#define OFF_DEG1   ((size_t)77799424)
#define OFF_DEG2   ((size_t)77807616)
#define OFF_ENT1   ((size_t)77815808)  // int2 x 131072 = 1MB
#define OFF_ENT2   ((size_t)78864384)  // 1MB

extern "C" void kernel_launch(void* const* d_in, const int* in_sizes, int n_in,
                              void* d_out, int out_size, void* d_ws, size_t ws_size,
                              hipStream_t stream) {
  (void)in_sizes; (void)n_in; (void)out_size; (void)ws_size;
  const float* out1 = (const float*)d_in[0];
  const float* out2 = (const float*)d_in[1];
  const float* c1 = (const float*)d_in[2];
  const float* c2 = (const float*)d_in[3];
  float* dout = (float*)d_out;
  char* ws = (char*)d_ws;

  float* interT = (float*)(ws + OFF_INTERT);
  float* s = (float*)(ws + OFF_S);
  u16* s_bf = (u16*)(ws + OFF_SBF);
  u16* T = (u16*)(ws + OFF_T);
  u16* Tt = (u16*)(ws + OFF_TT);
  u16* K = (u16*)(ws + OFF_K);
  u16* Kt = (u16*)(ws + OFF_KT);
  u16* o1b = (u16*)(ws + OFF_O1B);
  u16* o2b = (u16*)(ws + OFF_O2B);
  float* part = (float*)(ws + OFF_PART);
  float* c1a = (float*)(ws + OFF_C1A);
  float* bc2 = (float*)(ws + OFF_BC2);
  float* u = (float*)(ws + OFF_U);
  float* v = (float*)(ws + OFF_V);
  float* lp = (float*)(ws + OFF_LP);
  int* rp1 = (int*)(ws + OFF_RP1);
  int* rp2 = (int*)(ws + OFF_RP2);
  int* deg1 = (int*)(ws + OFF_DEG1);
  int* deg2 = (int*)(ws + OFF_DEG2);
  int2* ent1 = (int2*)(ws + OFF_ENT1);
  int2* ent2 = (int2*)(ws + OFF_ENT2);

  // ---- prep ----
  init_uv<<<8, 256, 0, stream>>>(u, v, dout);
  rowsq<<<NN1, 256, 0, stream>>>(c1, c1a);
  colsq_part<<<dim3(8, 16), 256, 0, stream>>>(c2, part);
  colsq_reduce<<<8, 256, 0, stream>>>(part, bc2);
  convbf<<<256, 256, 0, stream>>>(out1, o1b);
  convbf<<<256, 256, 0, stream>>>(out2, o2b);
  // interT[j,i] = exp(-(out2 @ out1^T)[j,i]) = inter_c[i,j]
  gemm_nt_exp<<<dim3(16, 16), 256, 0, stream>>>(o2b, o1b, DD, DD, DD, NN1, interT);
  sinit<<<2048, 256, 0, stream>>>(s, s_bf);
  // CSR builds
  csr_count<<<2048, 256, 0, stream>>>(c1, deg1);
  csr_scan<<<1, 256, 0, stream>>>(deg1, rp1);
  csr_fill<<<2048, 256, 0, stream>>>(c1, rp1, ent1);
  csr_count<<<2048, 256, 0, stream>>>(c2, deg2);
  csr_scan<<<1, 256, 0, stream>>>(deg2, rp2);
  csr_fill<<<2048, 256, 0, stream>>>(c2, rp2, ent2);

  // ---- outer loop ----
  for (int t = 0; t < 10; ++t) {
    // T = c1 @ s  (row-gather SpMM over CSR(c1), D = s_bf)
    spmm<0><<<2048, 256, 0, stream>>>(rp1, ent1, s_bf, T, nullptr, nullptr, nullptr);
    transpose_bf<<<dim3(32, 32), 256, 0, stream>>>(T, Tt);
    // Kt[j,:] from GWt[j,:] = sum_k c2[j,k] * Tt[k,:], fused exp epilogue
    spmm<1><<<2048, 256, 0, stream>>>(rp2, ent2, Tt, Kt, interT, c1a, bc2);
    transpose_bf<<<dim3(32, 32), 256, 0, stream>>>(Kt, K);
    for (int it = 0; it < 5; ++it) {
      matvec_div<<<NN1, 256, 0, stream>>>(K, v, u, 1.0f / 2048.0f);
      matvec_div<<<NN2, 256, 0, stream>>>(Kt, u, v, 1.0f / 2048.0f);
    }
    supdate<<<2048, 256, 0, stream>>>(s, s_bf, K, u, v);
  }

  // ---- loss ----
  lossdot_t<<<dim3(32, 32), 256, 0, stream>>>(interT, s, lp);
  lossreduce<<<1, 256, 0, stream>>>(lp, dout);
}

// Round 4
// 839.192 us; speedup vs baseline: 1.7090x; 1.2079x over previous
//
#include <hip/hip_runtime.h>
#include <hip/hip_bf16.h>

typedef unsigned short u16;
typedef unsigned char u8;
typedef __bf16 bf16x8 __attribute__((ext_vector_type(8)));
typedef float f32x4 __attribute__((ext_vector_type(4)));
typedef float f32x2 __attribute__((ext_vector_type(2)));
typedef unsigned short us8v __attribute__((ext_vector_type(8)));

#define NN1 2048
#define NN2 2048
#define DD  256

static __device__ __forceinline__ float bf2f(u16 u) {
  return __uint_as_float(((unsigned int)u) << 16);
}
static __device__ __forceinline__ u16 f2bf(float f) {
  __hip_bfloat16 h = __float2bfloat16(f);
  return __builtin_bit_cast(u16, h);
}
// decode 2 OCP e4m3 from low/high half-word of a 32-bit word (HI must be literal)
template <bool HI>
static __device__ __forceinline__ f32x2 fp8x2(unsigned int w) {
  return __builtin_amdgcn_cvt_pk_f32_fp8((int)w, HI);
}
// pack (a,b) as fp8 into selected half of old
template <bool HI>
static __device__ __forceinline__ unsigned int fp8pk(float a, float b, unsigned int old) {
  return (unsigned int)__builtin_amdgcn_cvt_pk_fp8_f32(a, b, (int)old, HI);
}
static __device__ __forceinline__ unsigned int pack4fp8(float a, float b, float c, float d) {
  unsigned int w = fp8pk<false>(a, b, 0u);
  return fp8pk<true>(c, d, w);
}

// block = 256 threads (4 waves)
static __device__ __forceinline__ float block_reduce_sum(float v) {
#pragma unroll
  for (int off = 32; off > 0; off >>= 1) v += __shfl_down(v, off, 64);
  __shared__ float tmp[4];
  const int tid = threadIdx.x;
  if ((tid & 63) == 0) tmp[tid >> 6] = v;
  __syncthreads();
  return tmp[0] + tmp[1] + tmp[2] + tmp[3];
}

static __device__ __forceinline__ void gload_lds16(const u16* g, u16* l) {
  __builtin_amdgcn_global_load_lds(
      (__attribute__((address_space(1))) void*)g,
      (__attribute__((address_space(3))) void*)l, 16, 0, 0);
}

// ---------------------------------------------------------------------------
// NT bf16 GEMM (prep): interT = exp(-(A @ B^T)) written f32 AND bf16
// ---------------------------------------------------------------------------
__global__ __launch_bounds__(256) void gemm_nt_exp(
    const u16* __restrict__ A, const u16* __restrict__ B,
    int K, int lda, int ldb, int ldo, float* __restrict__ outp,
    u16* __restrict__ outb) {
  __shared__ __align__(16) u16 As[128 * 32];
  __shared__ __align__(16) u16 Bs[128 * 32];
  const int tid = threadIdx.x;
  const int lane = tid & 63;
  const int w = tid >> 6;
  const int m0 = blockIdx.y * 128;
  const int n0 = blockIdx.x * 128;
  const int wr = (w >> 1) * 64;
  const int wc = (w & 1) * 64;
  const int srow = w * 16 + (lane >> 2);
  const int scol = (lane & 3) * 8;

  f32x4 acc[4][4] = {};

  for (int k0 = 0; k0 < K; k0 += 32) {
#pragma unroll
    for (int p = 0; p < 2; ++p) {
      gload_lds16(A + (size_t)(m0 + p * 64 + srow) * lda + (k0 + scol),
                  &As[(p * 64 + w * 16) * 32]);
      gload_lds16(B + (size_t)(n0 + p * 64 + srow) * ldb + (k0 + scol),
                  &Bs[(p * 64 + w * 16) * 32]);
    }
    __syncthreads();
    bf16x8 af[4], bg[4];
#pragma unroll
    for (int m = 0; m < 4; ++m)
      af[m] = *(const bf16x8*)&As[(wr + m * 16 + (lane & 15)) * 32 + (lane >> 4) * 8];
#pragma unroll
    for (int n = 0; n < 4; ++n)
      bg[n] = *(const bf16x8*)&Bs[(wc + n * 16 + (lane & 15)) * 32 + (lane >> 4) * 8];
#pragma unroll
    for (int m = 0; m < 4; ++m)
#pragma unroll
      for (int n = 0; n < 4; ++n)
        acc[m][n] = __builtin_amdgcn_mfma_f32_16x16x32_bf16(af[m], bg[n], acc[m][n], 0, 0, 0);
    __syncthreads();
  }

  const int cr = (lane >> 4) * 4;
  const int cc = lane & 15;
#pragma unroll
  for (int m = 0; m < 4; ++m)
#pragma unroll
    for (int n = 0; n < 4; ++n) {
      const int gc = n0 + wc + n * 16 + cc;
#pragma unroll
      for (int r = 0; r < 4; ++r) {
        const int gr = m0 + wr + m * 16 + cr + r;
        const float e = __expf(-acc[m][n][r]);
        outp[(size_t)gr * ldo + gc] = e;
        outb[(size_t)gr * ldo + gc] = f2bf(e);
      }
    }
}

// ---------------------------------------------------------------------------
// CSR build (deterministic)
// ---------------------------------------------------------------------------
__global__ __launch_bounds__(256) void csr_count(const float* __restrict__ M,
                                                 int* __restrict__ deg) {
  const int row = blockIdx.x;
  const int tid = threadIdx.x;
  int cnt = 0;
  for (int c = tid; c < 2048; c += 256) cnt += (M[(size_t)row * 2048 + c] != 0.0f);
#pragma unroll
  for (int off = 32; off > 0; off >>= 1) cnt += __shfl_down(cnt, off, 64);
  __shared__ int t4[4];
  if ((tid & 63) == 0) t4[tid >> 6] = cnt;
  __syncthreads();
  if (tid == 0) deg[row] = t4[0] + t4[1] + t4[2] + t4[3];
}

__global__ __launch_bounds__(256) void csr_scan(const int* __restrict__ deg,
                                                int* __restrict__ rptr) {
  __shared__ int sc[256];
  const int t = threadIdx.x;
  int loc[8];
  int tot = 0;
#pragma unroll
  for (int q = 0; q < 8; ++q) { loc[q] = deg[t * 8 + q]; tot += loc[q]; }
  sc[t] = tot;
  __syncthreads();
  for (int off = 1; off < 256; off <<= 1) {
    int val = (t >= off) ? sc[t - off] : 0;
    __syncthreads();
    sc[t] += val;
    __syncthreads();
  }
  int run = sc[t] - tot;
#pragma unroll
  for (int q = 0; q < 8; ++q) { rptr[t * 8 + q] = run; run += loc[q]; }
  if (t == 255) rptr[2048] = run;
}

__global__ __launch_bounds__(256) void csr_fill(const float* __restrict__ M,
                                                const int* __restrict__ rptr,
                                                int2* __restrict__ ent) {
  const int row = blockIdx.x;
  const int tid = threadIdx.x;
  const int lane = tid & 63;
  const int w = tid >> 6;
  __shared__ int wcnt[4];
  __shared__ int basech;
  if (tid == 0) basech = rptr[row];
  __syncthreads();
#pragma unroll 1
  for (int ch = 0; ch < 8; ++ch) {
    const int c = ch * 256 + tid;
    const float v = M[(size_t)row * 2048 + c];
    const bool p = (v != 0.0f);
    const unsigned long long mask = __ballot(p);
    if (lane == 0) wcnt[w] = __popcll(mask);
    __syncthreads();
    int woff = 0;
    for (int x = 0; x < w; ++x) woff += wcnt[x];
    const int pos = basech + woff + __popcll(mask & ((1ull << lane) - 1ull));
    if (p) ent[pos] = make_int2(c, __float_as_int(v));
    __syncthreads();
    if (tid == 0) basech += wcnt[0] + wcnt[1] + wcnt[2] + wcnt[3];
    __syncthreads();
  }
}

// ---------------------------------------------------------------------------
// Row-gather SpMM over fp8 D: out[row,:] = sum_e val_e * D[col_e,:]
// EPI 0: store fp8(acc * 2^-2)  (s*2^22 -> T*2^20)
// EPI 1: acc = GW*2^20; K'' = exp2(29 - 20*log2e*cost)
// ---------------------------------------------------------------------------
template <int EPI>
__global__ __launch_bounds__(256) void spmm(const int* __restrict__ rptr,
                                            const int2* __restrict__ ent,
                                            const u8* __restrict__ D,
                                            u8* __restrict__ outp,
                                            const u16* __restrict__ interT_bf,
                                            const float* __restrict__ c1a,
                                            const float* __restrict__ bc2) {
  __shared__ int2 se[256];
  const int row = blockIdx.x;
  const int tid = threadIdx.x;
  const int col0 = tid * 8;
  const int beg = rptr[row];
  const int end = rptr[row + 1];
  const int n = end - beg;
  if (tid < n && tid < 256) se[tid] = ent[beg + tid];
  __syncthreads();

  float a0[8] = {};
  float a1[8] = {};
  int e = 0;
  for (; e + 1 < n && e + 1 < 256; e += 2) {
    const int2 k0 = se[e];
    const int2 k1 = se[e + 1];
    const float v0 = __int_as_float(k0.y);
    const float v1 = __int_as_float(k1.y);
    const uint2 d0 = *(const uint2*)&D[((size_t)k0.x << 11) + col0];
    const uint2 d1 = *(const uint2*)&D[((size_t)k1.x << 11) + col0];
    const f32x2 p00 = fp8x2<false>(d0.x), p01 = fp8x2<true>(d0.x);
    const f32x2 p02 = fp8x2<false>(d0.y), p03 = fp8x2<true>(d0.y);
    const f32x2 p10 = fp8x2<false>(d1.x), p11 = fp8x2<true>(d1.x);
    const f32x2 p12 = fp8x2<false>(d1.y), p13 = fp8x2<true>(d1.y);
    a0[0] += v0 * p00[0]; a0[1] += v0 * p00[1]; a0[2] += v0 * p01[0]; a0[3] += v0 * p01[1];
    a0[4] += v0 * p02[0]; a0[5] += v0 * p02[1]; a0[6] += v0 * p03[0]; a0[7] += v0 * p03[1];
    a1[0] += v1 * p10[0]; a1[1] += v1 * p10[1]; a1[2] += v1 * p11[0]; a1[3] += v1 * p11[1];
    a1[4] += v1 * p12[0]; a1[5] += v1 * p12[1]; a1[6] += v1 * p13[0]; a1[7] += v1 * p13[1];
  }
  for (; e < n; ++e) {
    const int2 k0 = (e < 256) ? se[e] : ent[beg + e];
    const float v0 = __int_as_float(k0.y);
    const uint2 d0 = *(const uint2*)&D[((size_t)k0.x << 11) + col0];
    const f32x2 p00 = fp8x2<false>(d0.x), p01 = fp8x2<true>(d0.x);
    const f32x2 p02 = fp8x2<false>(d0.y), p03 = fp8x2<true>(d0.y);
    a0[0] += v0 * p00[0]; a0[1] += v0 * p00[1]; a0[2] += v0 * p01[0]; a0[3] += v0 * p01[1];
    a0[4] += v0 * p02[0]; a0[5] += v0 * p02[1]; a0[6] += v0 * p03[0]; a0[7] += v0 * p03[1];
  }
  float acc[8];
#pragma unroll
  for (int q = 0; q < 8; ++q) acc[q] = a0[q] + a1[q];

  uint2 o;
  if constexpr (EPI == 0) {
#pragma unroll
    for (int q = 0; q < 8; ++q) acc[q] = fminf(acc[q] * 0.25f, 440.0f);
    o.x = pack4fp8(acc[0], acc[1], acc[2], acc[3]);
    o.y = pack4fp8(acc[4], acc[5], acc[6], acc[7]);
  } else {
    const float bcj = bc2[row];
    const size_t base = ((size_t)row << 11) + col0;
    const us8v it = *(const us8v*)&interT_bf[base];
    const float4 aa0 = *(const float4*)&c1a[col0];
    const float4 aa1 = *(const float4*)&c1a[col0 + 4];
    const float aa[8] = {aa0.x, aa0.y, aa0.z, aa0.w, aa1.x, aa1.y, aa1.z, aa1.w};
    float k[8];
#pragma unroll
    for (int q = 0; q < 8; ++q) {
      const float cost = bf2f(it[q]) + 0.01f * (aa[q] + bcj) - 1.9073486e-8f * acc[q];
      k[q] = fminf(exp2f(29.0f - 28.8539008f * cost), 440.0f);
    }
    o.x = pack4fp8(k[0], k[1], k[2], k[3]);
    o.y = pack4fp8(k[4], k[5], k[6], k[7]);
  }
  *(uint2*)&outp[((size_t)row << 11) + col0] = o;
}

// ---------------------------------------------------------------------------
// y = M'' @ x (fp8 M, scaled), out[row] = anum / y[row]
// ---------------------------------------------------------------------------
__global__ __launch_bounds__(256) void matvec_div(const u8* __restrict__ M,
                                                  const float* __restrict__ x,
                                                  float* __restrict__ outv, float anum) {
  const int row = blockIdx.x;
  const int tid = threadIdx.x;
  const u8* rp = M + ((size_t)row << 11);
  const uint2 kw = *(const uint2*)&rp[tid * 8];
  const float4 x0 = *(const float4*)&x[tid * 8];
  const float4 x1 = *(const float4*)&x[tid * 8 + 4];
  const f32x2 q0 = fp8x2<false>(kw.x), q1 = fp8x2<true>(kw.x);
  const f32x2 q2 = fp8x2<false>(kw.y), q3 = fp8x2<true>(kw.y);
  float p = q0[0] * x0.x + q0[1] * x0.y + q1[0] * x0.z + q1[1] * x0.w +
            q2[0] * x1.x + q2[1] * x1.y + q3[0] * x1.z + q3[1] * x1.w;
  float s = block_reduce_sum(p);
  if (tid == 0) outv[row] = anum / s;
}

// ---------------------------------------------------------------------------
// fp8 (byte) transpose, 128x128 tiles
// ---------------------------------------------------------------------------
__global__ __launch_bounds__(256) void transpose_fp8(const u8* __restrict__ in,
                                                     u8* __restrict__ outp) {
  __shared__ u8 t[128][144];
  const int r0 = blockIdx.y * 128, c0 = blockIdx.x * 128;
  const int tid = threadIdx.x;
#pragma unroll
  for (int it = 0; it < 4; ++it) {
    const int idx = it * 256 + tid;
    const int r = idx >> 3, cb = (idx & 7) * 16;
    const uint4 w = *(const uint4*)&in[(size_t)(r0 + r) * 2048 + c0 + cb];
    const unsigned int ww[4] = {w.x, w.y, w.z, w.w};
#pragma unroll
    for (int wq = 0; wq < 4; ++wq) {
      const unsigned int x = ww[wq];
      t[cb + wq * 4 + 0][r] = x & 255u;
      t[cb + wq * 4 + 1][r] = (x >> 8) & 255u;
      t[cb + wq * 4 + 2][r] = (x >> 16) & 255u;
      t[cb + wq * 4 + 3][r] = x >> 24;
    }
  }
  __syncthreads();
#pragma unroll
  for (int it = 0; it < 4; ++it) {
    const int idx = it * 256 + tid;
    const int r = idx >> 3, cb = (idx & 7) * 16;
    *(uint4*)&outp[(size_t)(c0 + r) * 2048 + r0 + cb] = *(const uint4*)&t[r][cb];
  }
}

// ---------------------------------------------------------------------------
// s = 0.05*s + 0.95*u[i]*K''[i,j]*v[j]; writes s (f32) and s_fp8 = s*2^22
// ---------------------------------------------------------------------------
__global__ __launch_bounds__(256) void supdate(float* __restrict__ s,
                                               u8* __restrict__ s_f8,
                                               const u8* __restrict__ Kf8,
                                               const float* __restrict__ u,
                                               const float* __restrict__ v) {
  const int row = blockIdx.x;
  const int tid = threadIdx.x;
  const int col0 = tid * 8;
  const float uu = 0.95f * u[row];
  const size_t off = ((size_t)row << 11) + col0;
  const uint2 kw = *(const uint2*)&Kf8[off];
  const f32x2 q0 = fp8x2<false>(kw.x), q1 = fp8x2<true>(kw.x);
  const f32x2 q2 = fp8x2<false>(kw.y), q3 = fp8x2<true>(kw.y);
  const float kk[8] = {q0[0], q0[1], q1[0], q1[1], q2[0], q2[1], q3[0], q3[1]};
  const float4 v0 = *(const float4*)&v[col0];
  const float4 v1 = *(const float4*)&v[col0 + 4];
  const float vv[8] = {v0.x, v0.y, v0.z, v0.w, v1.x, v1.y, v1.z, v1.w};
  float4 s0 = *(const float4*)&s[off];
  float4 s1 = *(const float4*)&s[off + 4];
  float sv[8] = {s0.x, s0.y, s0.z, s0.w, s1.x, s1.y, s1.z, s1.w};
#pragma unroll
  for (int q = 0; q < 8; ++q) sv[q] = 0.05f * sv[q] + uu * kk[q] * vv[q];
  const float4 w0 = {sv[0], sv[1], sv[2], sv[3]};
  const float4 w1 = {sv[4], sv[5], sv[6], sv[7]};
  *(float4*)&s[off] = w0;
  *(float4*)&s[off + 4] = w1;
  const float SC = 4194304.0f;  // 2^22
  uint2 o;
  o.x = pack4fp8(fminf(sv[0] * SC, 440.0f), fminf(sv[1] * SC, 440.0f),
                 fminf(sv[2] * SC, 440.0f), fminf(sv[3] * SC, 440.0f));
  o.y = pack4fp8(fminf(sv[4] * SC, 440.0f), fminf(sv[5] * SC, 440.0f),
                 fminf(sv[6] * SC, 440.0f), fminf(sv[7] * SC, 440.0f));
  *(uint2*)&s_f8[off] = o;
}

// ---------------------------------------------------------------------------
// prep + loss
// ---------------------------------------------------------------------------
__global__ __launch_bounds__(256) void rowsq(const float* __restrict__ in,
                                             float* __restrict__ out) {
  const int row = blockIdx.x;
  const int tid = threadIdx.x;
  const float* rp = in + (size_t)row * 2048;
  float4 v0 = *(const float4*)&rp[tid * 8];
  float4 v1 = *(const float4*)&rp[tid * 8 + 4];
  float ss = v0.x * v0.x + v0.y * v0.y + v0.z * v0.z + v0.w * v0.w +
             v1.x * v1.x + v1.y * v1.y + v1.z * v1.z + v1.w * v1.w;
  float tot = block_reduce_sum(ss);
  if (tid == 0) out[row] = tot * (1.0f / 2048.0f);
}

__global__ __launch_bounds__(256) void convbf(const float* __restrict__ in,
                                              u16* __restrict__ outb) {
  const int i = (blockIdx.x * 256 + threadIdx.x) * 8;
  float4 v0 = *(const float4*)&in[i];
  float4 v1 = *(const float4*)&in[i + 4];
  us8v o;
  o[0] = f2bf(v0.x); o[1] = f2bf(v0.y); o[2] = f2bf(v0.z); o[3] = f2bf(v0.w);
  o[4] = f2bf(v1.x); o[5] = f2bf(v1.y); o[6] = f2bf(v1.z); o[7] = f2bf(v1.w);
  *(us8v*)&outb[i] = o;
}

__global__ __launch_bounds__(256) void sinit(float* __restrict__ s, u8* __restrict__ s_f8) {
  const int i = (blockIdx.x * 256 + threadIdx.x) * 8;
  const float val = 1.0f / (2048.0f * 2048.0f);  // 2^-22
  float4 f; f.x = f.y = f.z = f.w = val;
  *(float4*)&s[i] = f;
  *(float4*)&s[i + 4] = f;
  uint2 o;
  o.x = pack4fp8(1.0f, 1.0f, 1.0f, 1.0f);
  o.y = o.x;
  *(uint2*)&s_f8[i] = o;
}

__global__ __launch_bounds__(256) void init_uv(float* __restrict__ u, float* __restrict__ v,
                                               float* __restrict__ dout) {
  const int i = blockIdx.x * 256 + threadIdx.x;
  if (i < NN1) u[i] = 1.0f / 2048.0f;
  if (i < NN2) v[i] = 1.0f / 2048.0f;
  if (i == 0) dout[0] = 0.0f;
}

__global__ __launch_bounds__(256) void colsq_part(const float* __restrict__ c2,
                                                  float* __restrict__ part) {
  const int col = blockIdx.x * 256 + threadIdx.x;
  const int rb = blockIdx.y;
  float acc = 0.0f;
  for (int r = rb * 128; r < rb * 128 + 128; ++r) {
    const float x = c2[(size_t)r * 2048 + col];
    acc += x * x;
  }
  part[(size_t)rb * 2048 + col] = acc;
}
__global__ __launch_bounds__(256) void colsq_reduce(const float* __restrict__ part,
                                                    float* __restrict__ bc2) {
  const int col = blockIdx.x * 256 + threadIdx.x;
  float s = 0.0f;
#pragma unroll
  for (int rb = 0; rb < 16; ++rb) s += part[(size_t)rb * 2048 + col];
  bc2[col] = s * (1.0f / 2048.0f);
}

__global__ __launch_bounds__(256) void lossdot_t(const float* __restrict__ interT,
                                                 const float* __restrict__ s,
                                                 float* __restrict__ partial) {
  __shared__ float t[64][65];
  const int j0 = blockIdx.y * 64, i0 = blockIdx.x * 64;
  const int tid = threadIdx.x;
#pragma unroll
  for (int q = 0; q < 16; ++q) {
    const int idx = q * 256 + tid;
    const int r = idx >> 6, c = idx & 63;
    t[r][c] = interT[(size_t)(j0 + r) * 2048 + i0 + c];
  }
  __syncthreads();
  float acc = 0.0f;
#pragma unroll
  for (int q = 0; q < 16; ++q) {
    const int idx = q * 256 + tid;
    const int r = idx >> 6, c = idx & 63;
    acc += s[(size_t)(i0 + r) * 2048 + j0 + c] * t[c][r];
  }
  float tot = block_reduce_sum(acc);
  if (tid == 0) partial[blockIdx.y * 32 + blockIdx.x] = tot;
}

__global__ __launch_bounds__(256) void lossreduce(const float* __restrict__ partial,
                                                  float* __restrict__ dout) {
  float p = 0.0f;
  for (int i = threadIdx.x; i < 1024; i += 256) p += partial[i];
  float t = block_reduce_sum(p);
  if (threadIdx.x == 0) dout[0] = -t;
}

// ---------------------------------------------------------------------------
// workspace layout (bytes) — total ~67.3 MB
// ---------------------------------------------------------------------------
#define OFF_INTERT  ((size_t)0)         // f32 16MB
#define OFF_INTERTB ((size_t)16777216)  // bf16 8MB
#define OFF_S       ((size_t)25165824)  // f32 16MB
#define OFF_SF8     ((size_t)41943040)  // fp8 4MB
#define OFF_T       ((size_t)46137344)  // fp8 4MB
#define OFF_TT      ((size_t)50331648)  // fp8 4MB
#define OFF_KT      ((size_t)54525952)  // fp8 4MB
#define OFF_K       ((size_t)58720256)  // fp8 4MB
#define OFF_O1B     ((size_t)62914560)  // bf16 1MB
#define OFF_O2B     ((size_t)63963136)  // bf16 1MB
#define OFF_PART    ((size_t)65011712)  // f32 128KB
#define OFF_C1A     ((size_t)65142784)
#define OFF_BC2     ((size_t)65150976)
#define OFF_U       ((size_t)65159168)
#define OFF_V       ((size_t)65167360)
#define OFF_LP      ((size_t)65175552)
#define OFF_RP1     ((size_t)65183744)
#define OFF_RP2     ((size_t)65200128)
#define OFF_DEG1    ((size_t)65216512)
#define OFF_DEG2    ((size_t)65224704)
#define OFF_ENT1    ((size_t)65232896)  // int2 1MB
#define OFF_ENT2    ((size_t)66281472)  // int2 1MB

extern "C" void kernel_launch(void* const* d_in, const int* in_sizes, int n_in,
                              void* d_out, int out_size, void* d_ws, size_t ws_size,
                              hipStream_t stream) {
  (void)in_sizes; (void)n_in; (void)out_size; (void)ws_size;
  const float* out1 = (const float*)d_in[0];
  const float* out2 = (const float*)d_in[1];
  const float* c1 = (const float*)d_in[2];
  const float* c2 = (const float*)d_in[3];
  float* dout = (float*)d_out;
  char* ws = (char*)d_ws;

  float* interT = (float*)(ws + OFF_INTERT);
  u16* interTb = (u16*)(ws + OFF_INTERTB);
  float* s = (float*)(ws + OFF_S);
  u8* s_f8 = (u8*)(ws + OFF_SF8);
  u8* T = (u8*)(ws + OFF_T);
  u8* Tt = (u8*)(ws + OFF_TT);
  u8* Kt = (u8*)(ws + OFF_KT);
  u8* K = (u8*)(ws + OFF_K);
  u16* o1b = (u16*)(ws + OFF_O1B);
  u16* o2b = (u16*)(ws + OFF_O2B);
  float* part = (float*)(ws + OFF_PART);
  float* c1a = (float*)(ws + OFF_C1A);
  float* bc2 = (float*)(ws + OFF_BC2);
  float* u = (float*)(ws + OFF_U);
  float* v = (float*)(ws + OFF_V);
  float* lp = (float*)(ws + OFF_LP);
  int* rp1 = (int*)(ws + OFF_RP1);
  int* rp2 = (int*)(ws + OFF_RP2);
  int* deg1 = (int*)(ws + OFF_DEG1);
  int* deg2 = (int*)(ws + OFF_DEG2);
  int2* ent1 = (int2*)(ws + OFF_ENT1);
  int2* ent2 = (int2*)(ws + OFF_ENT2);

  // ---- prep ----
  init_uv<<<8, 256, 0, stream>>>(u, v, dout);
  rowsq<<<NN1, 256, 0, stream>>>(c1, c1a);
  colsq_part<<<dim3(8, 16), 256, 0, stream>>>(c2, part);
  colsq_reduce<<<8, 256, 0, stream>>>(part, bc2);
  convbf<<<256, 256, 0, stream>>>(out1, o1b);
  convbf<<<256, 256, 0, stream>>>(out2, o2b);
  gemm_nt_exp<<<dim3(16, 16), 256, 0, stream>>>(o2b, o1b, DD, DD, DD, NN1, interT, interTb);
  sinit<<<2048, 256, 0, stream>>>(s, s_f8);
  csr_count<<<2048, 256, 0, stream>>>(c1, deg1);
  csr_scan<<<1, 256, 0, stream>>>(deg1, rp1);
  csr_fill<<<2048, 256, 0, stream>>>(c1, rp1, ent1);
  csr_count<<<2048, 256, 0, stream>>>(c2, deg2);
  csr_scan<<<1, 256, 0, stream>>>(deg2, rp2);
  csr_fill<<<2048, 256, 0, stream>>>(c2, rp2, ent2);

  // ---- outer loop ----
  for (int t = 0; t < 10; ++t) {
    spmm<0><<<2048, 256, 0, stream>>>(rp1, ent1, s_f8, T, nullptr, nullptr, nullptr);
    transpose_fp8<<<dim3(16, 16), 256, 0, stream>>>(T, Tt);
    spmm<1><<<2048, 256, 0, stream>>>(rp2, ent2, Tt, Kt, interTb, c1a, bc2);
    transpose_fp8<<<dim3(16, 16), 256, 0, stream>>>(Kt, K);
    for (int it = 0; it < 5; ++it) {
      matvec_div<<<NN1, 256, 0, stream>>>(K, v, u, 1.0f / 2048.0f);   // u'' = u*2^-29
      matvec_div<<<NN2, 256, 0, stream>>>(Kt, u, v, 1.0f / 2048.0f);  // v exact
    }
    supdate<<<2048, 256, 0, stream>>>(s, s_f8, K, u, v);
  }

  // ---- loss ----
  lossdot_t<<<dim3(32, 32), 256, 0, stream>>>(interT, s, lp);
  lossreduce<<<1, 256, 0, stream>>>(lp, dout);
}